// Round 10
// baseline (405.317 us; speedup 1.0000x reference)
//
#include <hip/hip_runtime.h>

// 3x3 valid conv (NCHW/OIHW) + bias + relu(y)*min(y+3,6)/6, fp32.
// x: (N=4096, C=3, 32, 32), w: (16, 3, 3, 3), out: (N, 16, 30, 30).
//
// Round 14 = Round 13 resubmitted verbatim: the R13 bench died to an infra
// failure ("MI355X container failed twice" — no pytest/kernel error), and
// the diagnostic it carries is still the blocking unknown.
//
// DIAGNOSTIC PROBE (dur_us will regress ~+110us by design).
//  - Decomposition crisis: conv is counter-visible only when conv>fill;
//    4 of 5 recent rounds were blind. Fitting R5/R11 (the two measured
//    rounds) gives total = conv + fill + ~55us => current best (R6/R9)
//    conv ~ 85us vs 45us traffic floor; the deciding unknown is whether
//    through-L2 full-line stores RFO-fetch the poisoned output lines
//    (500MB => ~83us, matches measured) or not (270MB => ~45us).
//  - This kernel = best-guess-best structure: R9 hot loop (4-px groups,
//    b128+b64 x-reads, SGPR weight window, double-buffered sx, prefetch
//    after barrier, 1 barrier/img) + R12 wave-private staged epilogue with
//    PLAIN through-L2 float4 stores (nt removed: nt measured slower in both
//    granularities, R11=155 / R12~96 vs through-L2 ~85).
//  - Plus a ~110us s_sleep tail: all 1024 blocks co-resident (4/CU), so
//    dispatch dur = conv + sleep > fill(147) => conv surfaces in top-5 with
//    PURE single-pass FETCH/WRITE (sleep adds zero memory traffic).
//  - Readings (pre-committed): A) FETCH~25MB/WRITE~245MB => no RFO, ship
//    unpadded next round (~250-265 total). B) FETCH~260MB => RFO is
//    structural; try wide-burst nt or declare floor. C) WRITE>=350MB =>
//    epilogue still not full-line; asm-level bug hunt.

#define IMGS 4

__global__ __launch_bounds__(256, 4) void conv3x3_hswish(
    const float* __restrict__ x,
    const float* __restrict__ w,
    const float* __restrict__ bias,
    float* __restrict__ out)
{
    const int tid  = threadIdx.x;
    const int lane = tid & 63;
    const int wv   = tid >> 6;              // wave 0..3
    const int img0 = blockIdx.x * IMGS;

    // Double-buffered image; +8 pad covers the tail group's b64 overread.
    __shared__ __align__(16) float sx[2][3080];
    // Wave-private epilogue staging: [wave][4 oc][240 px].
    __shared__ __align__(16) float sy[4][960];

    // Slot: g = oh*8 + ow/4; threads 240..255 shadow slot 239, no stores.
    const int g  = tid < 240 ? tid : 239;
    const int oh = g >> 3;
    const int ow = (g & 7) << 2;            // 0,4,...,28
    const int xrow0 = oh * 32 + ow;
    const bool active = tid < 240;
    const bool full   = ow < 28;            // ow=28 group: only px 0,1 valid
    const int sybase = (oh & 7) * 30 + ow;  // row within wave's 8-row slab

    // Bias via scalar path (uniform -> SGPR).
    float bb[16];
    #pragma unroll
    for (int oc = 0; oc < 16; ++oc) bb[oc] = bias[oc];

    // Prefetch image 0.
    float4 px0, px1, px2;
    {
        const float4* xg = (const float4*)(x + (size_t)img0 * 3072);
        px0 = xg[tid]; px1 = xg[tid + 256]; px2 = xg[tid + 512];
    }

    #pragma unroll 1
    for (int im = 0; im < IMGS; ++im) {
        float* buf = sx[im & 1];
        {   // Commit staged image.
            float4* s4 = (float4*)buf;
            s4[tid] = px0; s4[tid + 256] = px1; s4[tid + 512] = px2;
        }
        __syncthreads();

        // Next image's loads fly under the whole compute phase.
        if (im + 1 < IMGS) {
            const float4* xg =
                (const float4*)(x + (size_t)(img0 + im + 1) * 3072);
            px0 = xg[tid]; px1 = xg[tid + 256]; px2 = xg[tid + 512];
        }
        __builtin_amdgcn_sched_barrier(0);   // pin prefetch issue here

        float acc[4][16];
        #pragma unroll
        for (int k = 0; k < 4; ++k)
            #pragma unroll
            for (int oc = 0; oc < 16; ++oc) acc[k][oc] = 0.f;

        // Hot loop: dynamic ic, static (kh,kw); weights via s_load/SGPR.
        #pragma unroll 1
        for (int ic = 0; ic < 3; ++ic) {
            const float* __restrict__ wq = w + ic * 9;
            const float* xr = buf + (ic << 10) + xrow0;
            #pragma unroll
            for (int kh = 0; kh < 3; ++kh) {
                const float4 v4 = *(const float4*)(xr + kh * 32);
                const float2 v2 = *(const float2*)(xr + kh * 32 + 4);
                const float xv[6] = {v4.x, v4.y, v4.z, v4.w, v2.x, v2.y};
                #pragma unroll
                for (int kw = 0; kw < 3; ++kw) {
                    float ws[16];
                    #pragma unroll
                    for (int oc = 0; oc < 16; ++oc)
                        ws[oc] = wq[oc * 27 + kh * 3 + kw];   // uniform->SGPR
                    #pragma unroll
                    for (int k = 0; k < 4; ++k) {
                        const float xx = xv[k + kw];          // static index
                        #pragma unroll
                        for (int oc = 0; oc < 16; ++oc)
                            acc[k][oc] = fmaf(xx, ws[oc], acc[k][oc]);
                    }
                }
            }
        }

        // Epilogue: 4 oc-chunks. Per chunk: wave-private LDS transpose
        // (no barriers, in-wave ds ordering), then PLAIN through-L2 float4
        // stores of contiguous full 64B lines (wave = 960B span per oc).
        float* syw  = sy[wv];
        float* outn = out + (size_t)(img0 + im) * 14400 + wv * 240;
        const int lim = (wv < 3) ? 60 : 45;  // wave 3 spans 6 rows = 180 fl
        #pragma unroll
        for (int ch = 0; ch < 4; ++ch) {
            if (active) {
                #pragma unroll
                for (int i = 0; i < 4; ++i) {
                    const int oc = ch * 4 + i;
                    const float y0 = acc[0][oc] + bb[oc];
                    const float y1 = acc[1][oc] + bb[oc];
                    float2 r01;
                    r01.x = fmaxf(y0, 0.f) * fminf(fmaf(y0, 1.f/6.f, 0.5f), 1.f);
                    r01.y = fmaxf(y1, 0.f) * fminf(fmaf(y1, 1.f/6.f, 0.5f), 1.f);
                    *(float2*)(syw + i * 240 + sybase) = r01;
                    if (full) {
                        const float y2 = acc[2][oc] + bb[oc];
                        const float y3 = acc[3][oc] + bb[oc];
                        float2 r23;
                        r23.x = fmaxf(y2, 0.f) * fminf(fmaf(y2, 1.f/6.f, 0.5f), 1.f);
                        r23.y = fmaxf(y3, 0.f) * fminf(fmaf(y3, 1.f/6.f, 0.5f), 1.f);
                        *(float2*)(syw + i * 240 + sybase + 2) = r23;
                    }
                }
            }
            if (lane < lim) {
                #pragma unroll
                for (int i = 0; i < 4; ++i) {
                    const int oc = ch * 4 + i;
                    const float4 v = *(const float4*)(syw + i * 240 + lane * 4);
                    *(float4*)(outn + oc * 900 + lane * 4) = v;
                }
            }
        }
        // No trailing barrier: next iteration writes the OTHER sx buffer,
        // and sy is wave-private.
    }

    // ---- Diagnostic tail: ~110us sleep (32 x s_sleep(127) ~ 8128 clk).
    // All blocks are co-resident, so dispatch duration = conv + sleep,
    // pushing conv above the ~147us fills into rocprof's top-5 with pure
    // single-pass memory counters. REMOVE in the next round.
    #pragma unroll 1
    for (int i = 0; i < 32; ++i) __builtin_amdgcn_s_sleep(127);
}

extern "C" void kernel_launch(void* const* d_in, const int* in_sizes, int n_in,
                              void* d_out, int out_size, void* d_ws, size_t ws_size,
                              hipStream_t stream) {
    const float* x    = (const float*)d_in[0];
    const float* w    = (const float*)d_in[1];
    const float* bias = (const float*)d_in[2];
    float* out        = (float*)d_out;

    const int N = in_sizes[0] / (3 * 32 * 32);  // 4096
    conv3x3_hswish<<<N / IMGS, 256, 0, stream>>>(x, w, bias, out);
}